// Round 10
// baseline (278.170 us; speedup 1.0000x reference)
//
#include <hip/hip_runtime.h>
#include <stdint.h>

// Keep IoU arithmetic bit-identical to an IEEE no-FMA reference:
#pragma clang fp contract(off)

#define BB   8
#define NN   2048
#define CC   32
#define WORDS 64           // uint32 words per 2048-bit row mask
#define NBLK 64            // rank blocks of 32
#define NMS_THR 0.45f
#define PRE_THR 0.005f
#define PADI(i) ((((i) >> 5) * 33) + ((i) & 31))   // padded SoA index
#define KPAD(i) ((i) + ((i) >> 4))                 // u64 key pad

typedef unsigned long long u64;

// ---------------- K1: per-image adjacency bitmask ----------------
__global__ __launch_bounds__(256) void adj_kernel(const float* __restrict__ bbs,
                                                  uint32_t* __restrict__ adj) {
    __shared__ float sx1[2112], sy1[2112], sx2[2112], sy2[2112];
    const int b = blockIdx.y;
    const int t = threadIdx.x;
    const float4* bp = (const float4*)bbs + (size_t)b * NN;
    for (int i = t; i < NN; i += 256) {
        float4 v = bp[i];
        int p = PADI(i);
        sx1[p] = v.x; sy1[p] = v.y; sx2[p] = v.z; sy2[p] = v.w;
    }
    __syncthreads();

    const int wave = t >> 6, lane = t & 63;
    const int row0 = blockIdx.x * 16 + wave * 4;
    const float THI = 0.45f * 1.00002f;
    const float TLO = 0.45f * 0.99998f;

    float ax1[4], ay1[4], ax2[4], ay2[4], areaA[4];
#pragma unroll
    for (int r = 0; r < 4; ++r) {
        int p = PADI(row0 + r);
        ax1[r] = sx1[p]; ay1[r] = sy1[p]; ax2[r] = sx2[p]; ay2[r] = sy2[p];
        areaA[r] = (ax2[r] - ax1[r]) * (ay2[r] - ay1[r]);
    }
    uint32_t w[4] = {0, 0, 0, 0};
#pragma unroll 4
    for (int j = 0; j < 32; ++j) {
        int p = lane * 33 + j;                 // bank (lane+j)%32: 2-way = free
        float bx1 = sx1[p], by1 = sy1[p], bx2 = sx2[p], by2 = sy2[p];
        float areaB = (bx2 - bx1) * (by2 - by1);
#pragma unroll
        for (int r = 0; r < 4; ++r) {
            float ltx = fmaxf(ax1[r], bx1), lty = fmaxf(ay1[r], by1);
            float rbx = fminf(ax2[r], bx2), rby = fminf(ay2[r], by2);
            float ww = fmaxf(rbx - ltx, 0.0f);
            float hh = fmaxf(rby - lty, 0.0f);
            float inter = ww * hh;
            float uni  = (areaA[r] + areaB) - inter;
            float unim = fmaxf(uni, 1e-12f);
            float q1 = inter * __builtin_amdgcn_rcpf(unim);
            bool hi = q1 > THI;
            bool lo = q1 < TLO;
            bool adjb;
            if (__builtin_expect(__any((int)!(hi || lo)), 0))
                adjb = (inter / unim) > NMS_THR;   // exact IEEE div, rare
            else
                adjb = hi;
            if (adjb) w[r] |= (1u << j);
        }
    }
#pragma unroll
    for (int r = 0; r < 4; ++r) {
        int row = row0 + r;
        uint32_t dmask = (lane == (row >> 5)) ? ~(1u << (row & 31)) : 0xFFFFFFFFu;
        adj[((size_t)b * NN + row) * WORDS + lane] = w[r] & dmask;
    }
}

// ---------------- K2: per-(b,c) bitonic sort, 1024 threads ----------------
__device__ __forceinline__ void ce_reg(u64& a, u64& b, bool up) {
    u64 mn = (a < b) ? a : b;
    u64 mx = (a < b) ? b : a;
    a = up ? mx : mn;
    b = up ? mn : mx;
}

__global__ __launch_bounds__(1024) void sort_kernel(const float* __restrict__ conf,
                                                    uint32_t* __restrict__ wsOrd) {
    __shared__ u64 keys[2176];   // KPAD(2047)=2174
    const int bc = blockIdx.x;
    const int t  = threadIdx.x;
    const float* cf = conf + (size_t)bc * NN;

    if (t < 512) {
        const int g = 4 * t;
        float4 v = ((const float4*)cf)[t];
        float f0 = (v.x > PRE_THR) ? v.x : 0.0f;
        float f1 = (v.y > PRE_THR) ? v.y : 0.0f;
        float f2 = (v.z > PRE_THR) ? v.z : 0.0f;
        float f3 = (v.w > PRE_THR) ? v.w : 0.0f;
        u64 a0 = ((u64)__float_as_uint(f0) << 32) | (uint32_t)(NN - 1 - (g + 0));
        u64 a1 = ((u64)__float_as_uint(f1) << 32) | (uint32_t)(NN - 1 - (g + 1));
        u64 a2 = ((u64)__float_as_uint(f2) << 32) | (uint32_t)(NN - 1 - (g + 2));
        u64 a3 = ((u64)__float_as_uint(f3) << 32) | (uint32_t)(NN - 1 - (g + 3));
        ce_reg(a0, a1, true);
        ce_reg(a2, a3, false);
        bool up4 = ((g & 4) == 0);
        ce_reg(a0, a2, up4); ce_reg(a1, a3, up4);
        ce_reg(a0, a1, up4); ce_reg(a2, a3, up4);
        keys[KPAD(g + 0)] = a0; keys[KPAD(g + 1)] = a1;
        keys[KPAD(g + 2)] = a2; keys[KPAD(g + 3)] = a3;
    }
    __syncthreads();

    for (unsigned k = 8; k <= NN; k <<= 1) {
        unsigned j = k >> 1;
        while (j >= 2) {
            const unsigned h = j >> 1;
            if (t < 512) {
                unsigned g  = (((unsigned)t & ~(h - 1)) << 2) | ((unsigned)t & (h - 1));
                bool up = ((g & k) == 0);
                u64 e0 = keys[KPAD(g)];
                u64 e1 = keys[KPAD(g + h)];
                u64 e2 = keys[KPAD(g + j)];
                u64 e3 = keys[KPAD(g + j + h)];
                ce_reg(e0, e2, up); ce_reg(e1, e3, up);
                ce_reg(e0, e1, up); ce_reg(e2, e3, up);
                keys[KPAD(g)]         = e0;
                keys[KPAD(g + h)]     = e1;
                keys[KPAD(g + j)]     = e2;
                keys[KPAD(g + j + h)] = e3;
            }
            __syncthreads();
            j >>= 2;
        }
        if (j == 1) {
            unsigned i  = (unsigned)t << 1;
            bool up = ((i & k) == 0);
            u64 a = keys[KPAD(i)], d = keys[KPAD(i + 1)];
            ce_reg(a, d, up);
            keys[KPAD(i)] = a; keys[KPAD(i + 1)] = d;
            __syncthreads();
        }
    }

    uint32_t* ov = wsOrd + (size_t)bc * NN;
    for (int r = t; r < NN; r += 1024) {
        u64 kk = keys[KPAD(r)];
        uint32_t idx = (uint32_t)(NN - 1) - (uint32_t)(kk & 0xffffffffu);
        uint32_t nz  = ((uint32_t)(kk >> 32) != 0u) ? 0x10000u : 0u;
        ov[r] = idx | nz;
    }
}

// ---------------- K3: rank-space sub-adjacency extraction ----------------
__global__ __launch_bounds__(256) void extract_kernel(const uint32_t* __restrict__ adj,
                                                      const uint32_t* __restrict__ wsOrd,
                                                      uint32_t* __restrict__ wsM) {
    const int blkid = blockIdx.x;
    const int bc = blkid >> 3, chunk = blkid & 7;
    const int b  = bc >> 5;
    const int t = threadIdx.x, wv = t >> 6, lane = t & 63, e = lane & 31, h = lane >> 5;
    const uint32_t* ov = wsOrd + (size_t)bc * NN;
    const uint32_t* ab = adj + (size_t)b * NN * WORDS;

    for (int blk = chunk * 8 + wv; blk < chunk * 8 + 8; blk += 4) {
        uint32_t ue = ov[blk * 32 + e];
        int widx = (int)((ue & 0xffffu) >> 5);
        int bpos = (int)(ue & 31u);
        uint32_t wb[16];
#pragma unroll
        for (int k = 0; k < 16; ++k) {
            uint32_t ud = ov[blk * 32 + k * 2 + h] & 0xffffu;
            wb[k] = ab[(size_t)ud * WORDS + widx];
        }
        uint32_t vM = 0;
#pragma unroll
        for (int k = 0; k < 16; ++k) {
            unsigned long long bal = __ballot(((wb[k] >> bpos) & 1u) != 0u);
            vM = (lane == 2 * k    ) ? (uint32_t)bal         : vM;
            vM = (lane == 2 * k + 1) ? (uint32_t)(bal >> 32) : vM;
        }
        if (lane < 32)
            wsM[(size_t)bc * NN + blk * 32 + lane] = vM & (0xFFFFFFFEu << lane);
    }
}

// ---------------- K4: dual-class register-resident serial scan ----------------
// One wave handles TWO classes (same image -> shared adj base). The two serial
// chains are independent; interleaving them on one wave fills the per-instruction
// hazard bubbles that made the single-chain version ~9 cy/instr (R8 post-mortem).
// R8-proven structure per chain (bpermute at resolve head, 2-deep row ping-pong,
// clamped tail prefetch); all array indices compile-time -> no scratch.
#define PREF(u_, r_)                                                    \
  {                                                                     \
    _Pragma("unroll")                                                   \
    for (int d = 0; d < 32; ++d) {                                      \
      int ud_ = __builtin_amdgcn_readlane((int)(u_), d) & 0xffff;       \
      r_[d] = rowp[(size_t)ud_ * WORDS];                                \
    }                                                                   \
  }

#define RES(S_, u_, m_, r_)                                             \
  {                                                                     \
    int pm_ = __builtin_amdgcn_ds_bpermute(                             \
        (int)((((u_) & 0xffffu) >> 5) << 2), (int)(S_));                \
    bool a0_ = ((((u_) >> 16) & 1u) != 0u) &&                           \
               (((pm_ >> ((u_) & 31u)) & 1) == 0);                      \
    uint32_t alive_ = (uint32_t)__ballot((int)a0_);                     \
    _Pragma("unroll")                                                   \
    for (int d = 0; d < 32; ++d) {                                      \
      uint32_t md_ = (uint32_t)__builtin_amdgcn_readlane((int)(m_), d); \
      alive_ = (alive_ & (1u << d)) ? (alive_ & ~md_) : alive_;         \
    }                                                                   \
    uint32_t acc_ = 0;                                                  \
    _Pragma("unroll")                                                   \
    for (int d = 0; d < 32; ++d)                                        \
      acc_ |= (alive_ & (1u << d)) ? r_[d] : 0u;                        \
    S_ |= acc_;                                                         \
  }

__global__ __launch_bounds__(64, 1) void scan_kernel(const float* __restrict__ conf,
                                                     const uint32_t* __restrict__ adj,
                                                     const uint32_t* __restrict__ wsOrd,
                                                     const uint32_t* __restrict__ wsM,
                                                     float* __restrict__ out) {
    __shared__ uint32_t ordLA[NN], MlA[NN];   // 16 KB (class A)
    __shared__ uint32_t ordLB[NN], MlB[NN];   // 16 KB (class B)
    __shared__ uint32_t SarrA[WORDS], SarrB[WORDS];
    const int g  = blockIdx.x;                 // 128 blocks = 8 images x 16 pairs
    const int b  = g >> 4;
    const int bc0 = b * CC + (g & 15) * 2;     // class pair (c, c+1)
    const int bc1 = bc0 + 1;
    const int lane = threadIdx.x;
    const int lane31 = lane & 31;
    const uint32_t* const rowp = adj + (size_t)b * NN * WORDS + lane;  // shared image
    const float* cfA = conf + (size_t)bc0 * NN;
    const float* cfB = conf + (size_t)bc1 * NN;
    float* opA = out + (size_t)bc0 * NN;
    float* opB = out + (size_t)bc1 * NN;

    // Stage ord + M for both classes into LDS (uint4-wide, coalesced).
    {
        const uint4* oA = (const uint4*)(wsOrd + (size_t)bc0 * NN);
        const uint4* oB = (const uint4*)(wsOrd + (size_t)bc1 * NN);
        const uint4* mA = (const uint4*)(wsM   + (size_t)bc0 * NN);
        const uint4* mB = (const uint4*)(wsM   + (size_t)bc1 * NN);
        for (int i = lane; i < NN / 4; i += 64) {
            ((uint4*)ordLA)[i] = oA[i];
            ((uint4*)MlA)[i]   = mA[i];
            ((uint4*)ordLB)[i] = oB[i];
            ((uint4*)MlB)[i]   = mB[i];
        }
    }
    __syncthreads();

    uint32_t SA = 0, SB = 0;
    uint32_t rA0[32], rA1[32], rB0[32], rB1[32];
    uint32_t uA0 = ordLA[lane31],      mA0 = MlA[lane31];
    uint32_t uA1 = ordLA[32 + lane31], mA1 = MlA[32 + lane31];
    uint32_t uB0 = ordLB[lane31],      mB0 = MlB[lane31];
    uint32_t uB1 = ordLB[32 + lane31], mB1 = MlB[32 + lane31];
    PREF(uA0, rA0);
    PREF(uB0, rB0);
    PREF(uA1, rA1);
    PREF(uB1, rB1);

    for (int k = 0; k < NBLK; k += 2) {
        int k2 = (k + 2 > 63) ? 63 : k + 2;
        int k3 = (k + 3 > 63) ? 63 : k + 3;
        // ---- blocks k (buffers *0), A then B interleaved ----
        uint32_t uNA = ordLA[k2 * 32 + lane31], mNA = MlA[k2 * 32 + lane31];
        uint32_t uNB = ordLB[k2 * 32 + lane31], mNB = MlB[k2 * 32 + lane31];
        RES(SA, uA0, mA0, rA0);
        uA0 = uNA; mA0 = mNA; PREF(uA0, rA0);
        RES(SB, uB0, mB0, rB0);
        uB0 = uNB; mB0 = mNB; PREF(uB0, rB0);
        // ---- blocks k+1 (buffers *1) ----
        uint32_t uNA1 = ordLA[k3 * 32 + lane31], mNA1 = MlA[k3 * 32 + lane31];
        uint32_t uNB1 = ordLB[k3 * 32 + lane31], mNB1 = MlB[k3 * 32 + lane31];
        RES(SA, uA1, mA1, rA1);
        uA1 = uNA1; mA1 = mNA1; PREF(uA1, rA1);
        RES(SB, uB1, mB1, rB1);
        uB1 = uNB1; mB1 = mNB1; PREF(uB1, rB1);
    }

    SarrA[lane] = SA;
    SarrB[lane] = SB;
    __syncthreads();

    // Output both classes: float4 per lane per iter.
#pragma unroll
    for (int it = 0; it < 8; ++it) {
        int i4 = it * 256 + lane * 4;
        float4 v = ((const float4*)cfA)[it * 64 + lane];
        uint32_t sw = SarrA[i4 >> 5];
        float4 o;
        o.x = (v.x > PRE_THR && !((sw >> ((i4 + 0) & 31)) & 1u)) ? v.x : 0.0f;
        o.y = (v.y > PRE_THR && !((sw >> ((i4 + 1) & 31)) & 1u)) ? v.y : 0.0f;
        o.z = (v.z > PRE_THR && !((sw >> ((i4 + 2) & 31)) & 1u)) ? v.z : 0.0f;
        o.w = (v.w > PRE_THR && !((sw >> ((i4 + 3) & 31)) & 1u)) ? v.w : 0.0f;
        ((float4*)opA)[it * 64 + lane] = o;
    }
#pragma unroll
    for (int it = 0; it < 8; ++it) {
        int i4 = it * 256 + lane * 4;
        float4 v = ((const float4*)cfB)[it * 64 + lane];
        uint32_t sw = SarrB[i4 >> 5];
        float4 o;
        o.x = (v.x > PRE_THR && !((sw >> ((i4 + 0) & 31)) & 1u)) ? v.x : 0.0f;
        o.y = (v.y > PRE_THR && !((sw >> ((i4 + 1) & 31)) & 1u)) ? v.y : 0.0f;
        o.z = (v.z > PRE_THR && !((sw >> ((i4 + 2) & 31)) & 1u)) ? v.z : 0.0f;
        o.w = (v.w > PRE_THR && !((sw >> ((i4 + 3) & 31)) & 1u)) ? v.w : 0.0f;
        ((float4*)opB)[it * 64 + lane] = o;
    }
}

// ---------------- Fallback (ws too small): monolithic ----------------
__global__ __launch_bounds__(256) void nms_fallback(const float* __restrict__ conf,
                                                    const uint32_t* __restrict__ adj,
                                                    float* __restrict__ out) {
    __shared__ unsigned long long keys[NN];
    __shared__ uint32_t ordv[NN];
    __shared__ uint32_t Mlds[NBLK * 32];
    __shared__ uint32_t Sarr[WORDS];
    const int bc = blockIdx.x;
    const int b  = bc >> 5;
    const int t  = threadIdx.x;
    const float* cf = conf + (size_t)bc * NN;
    const uint32_t* const abase = adj + (size_t)b * NN * WORDS;

    for (int i = t; i < NN; i += 256) {
        float v  = cf[i];
        float vt = (v > PRE_THR) ? v : 0.0f;
        keys[i] = ((unsigned long long)__float_as_uint(vt) << 32) | (uint32_t)(NN - 1 - i);
    }
    __syncthreads();
    for (unsigned k = 2; k <= NN; k <<= 1)
        for (unsigned j = k >> 1; j > 0; j >>= 1) {
            for (unsigned p = t; p < NN / 2; p += 256) {
                unsigned i  = ((p & ~(j - 1)) << 1) | (p & (j - 1));
                unsigned ij = i | j;
                unsigned long long a = keys[i], d = keys[ij];
                bool up = ((i & k) == 0);
                if (up ? (a < d) : (a > d)) { keys[i] = d; keys[ij] = a; }
            }
            __syncthreads();
        }
    for (int r = t; r < NN; r += 256) {
        unsigned long long kk = keys[r];
        uint32_t idx = (uint32_t)(NN - 1) - (uint32_t)(kk & 0xffffffffu);
        uint32_t nz  = ((uint32_t)(kk >> 32) != 0u) ? 0x10000u : 0u;
        ordv[r] = idx | nz;
    }
    __syncthreads();
    {
        const int wid = t >> 6, lane = t & 63, e = lane & 31, h = lane >> 5;
        for (int blk = wid * 16; blk < wid * 16 + 16; ++blk) {
            uint32_t ue = ordv[blk * 32 + e];
            int widx = (int)((ue & 0xffffu) >> 5);
            int bpos = (int)(ue & 31u);
            uint32_t vM = 0;
#pragma unroll
            for (int half = 0; half < 2; ++half) {
                uint32_t wbuf[8];
#pragma unroll
                for (int k = 0; k < 8; ++k) {
                    int d = half * 16 + k * 2 + h;
                    uint32_t ud = ordv[blk * 32 + d] & 0xffffu;
                    wbuf[k] = abase[(size_t)ud * WORDS + widx];
                }
#pragma unroll
                for (int k = 0; k < 8; ++k) {
                    int d0 = half * 16 + k * 2;
                    unsigned long long bal = __ballot(((wbuf[k] >> bpos) & 1u) != 0u);
                    vM = (lane == d0    ) ? (uint32_t)bal         : vM;
                    vM = (lane == d0 + 1) ? (uint32_t)(bal >> 32) : vM;
                }
            }
            if (lane < 32) Mlds[blk * 32 + lane] = vM;
        }
    }
    __syncthreads();
    if (t < 64) {
        const int lane = t;
        const uint32_t* const rowp = abase + lane;
        uint32_t S = 0;
        uint32_t rbA[32], rbB[32];
        uint32_t u_c, m_c, u_n, m_n;
        u_c = ordv[lane & 31];
        m_c = Mlds[lane & 31];
#pragma unroll
        for (int d = 0; d < 32; ++d) {
            int ud = __builtin_amdgcn_readlane((int)u_c, d) & 0xffff;
            rbA[d] = rowp[(size_t)ud * WORDS];
        }
        auto do_block = [&](int blk, uint32_t (&rbC)[32], uint32_t (&rbN)[32]) {
            u_n = 0; m_n = 0;
            if (blk < 63) {
                u_n = ordv[(blk + 1) * 32 + (lane & 31)];
                m_n = Mlds[(blk + 1) * 32 + (lane & 31)];
#pragma unroll
                for (int d = 0; d < 32; ++d) {
                    int ud = __builtin_amdgcn_readlane((int)u_n, d) & 0xffff;
                    rbN[d] = rowp[(size_t)ud * WORDS];
                }
            }
            int wq  = (int)(((u_c & 0xffffu) >> 5) << 2);
            int bpv = (int)(u_c & 31u);
            int pm  = __builtin_amdgcn_ds_bpermute(wq, (int)S);
            bool a0 = (((u_c >> 16) & 1u) != 0u) && (((pm >> bpv) & 1) == 0);
            uint32_t alive = (uint32_t)__ballot((int)a0);
#pragma unroll
            for (int d = 0; d < 32; ++d) {
                uint32_t rowd = (uint32_t)__builtin_amdgcn_readlane((int)m_c, d);
                uint32_t mk = rowd & (0xFFFFFFFEu << d);
                alive = (alive & (1u << d)) ? (alive & ~mk) : alive;
            }
            uint32_t acc = 0;
#pragma unroll
            for (int d = 0; d < 32; ++d)
                acc |= (alive & (1u << d)) ? rbC[d] : 0u;
            S |= acc;
            u_c = u_n; m_c = m_n;
        };
        for (int blk = 0; blk < 64; blk += 2) {
            do_block(blk,     rbA, rbB);
            do_block(blk + 1, rbB, rbA);
        }
        Sarr[lane] = S;
    }
    __syncthreads();
    float* op = out + (size_t)bc * NN;
    for (int i = t; i < NN; i += 256) {
        float v = cf[i];
        bool sup = (Sarr[i >> 5] >> (i & 31)) & 1u;
        op[i] = (v > PRE_THR && !sup) ? v : 0.0f;
    }
}

extern "C" void kernel_launch(void* const* d_in, const int* in_sizes, int n_in,
                              void* d_out, int out_size, void* d_ws, size_t ws_size,
                              hipStream_t stream) {
    const float* bbs  = (const float*)d_in[0];   // [8,2048,4]
    const float* conf = (const float*)d_in[1];   // [8,32,2048]
    float* out = (float*)d_out;                  // [8,32,2048]

    const size_t adjB = (size_t)BB * NN * WORDS * sizeof(uint32_t);   // 4 MB
    const size_t ordB = (size_t)BB * CC * NN * sizeof(uint32_t);      // 2 MB
    const size_t mB   = ordB;                                          // 2 MB
    uint32_t* adj = (uint32_t*)d_ws;

    if (ws_size >= adjB + ordB + mB) {
        uint32_t* wsOrd = (uint32_t*)((char*)d_ws + adjB);
        uint32_t* wsM   = (uint32_t*)((char*)d_ws + adjB + ordB);
        adj_kernel    <<<dim3(NN / 16, BB), 256, 0, stream>>>(bbs, adj);
        sort_kernel   <<<BB * CC, 1024, 0, stream>>>(conf, wsOrd);
        extract_kernel<<<BB * CC * 8, 256, 0, stream>>>(adj, wsOrd, wsM);
        scan_kernel   <<<BB * CC / 2, 64, 0, stream>>>(conf, adj, wsOrd, wsM, out);
    } else if (ws_size >= adjB) {
        adj_kernel  <<<dim3(NN / 16, BB), 256, 0, stream>>>(bbs, adj);
        nms_fallback<<<BB * CC, 256, 0, stream>>>(conf, adj, out);
    }
}

// Round 11
// 265.451 us; speedup vs baseline: 1.0479x; 1.0479x over previous
//
#include <hip/hip_runtime.h>
#include <stdint.h>

// Keep IoU arithmetic bit-identical to an IEEE no-FMA reference:
#pragma clang fp contract(off)

#define BB   8
#define NN   2048
#define CC   32
#define WORDS 64           // uint32 words per 2048-bit row mask
#define NBLK 64            // rank blocks of 32
#define NMS_THR 0.45f
#define PRE_THR 0.005f
#define PADI(i) ((((i) >> 5) * 33) + ((i) & 31))   // padded SoA index
#define KPAD(i) ((i) + ((i) >> 4))                 // u64 key pad

typedef unsigned long long u64;

// ---------------- K1: per-image adjacency bitmask ----------------
__global__ __launch_bounds__(256) void adj_kernel(const float* __restrict__ bbs,
                                                  uint32_t* __restrict__ adj) {
    __shared__ float sx1[2112], sy1[2112], sx2[2112], sy2[2112];
    const int b = blockIdx.y;
    const int t = threadIdx.x;
    const float4* bp = (const float4*)bbs + (size_t)b * NN;
    for (int i = t; i < NN; i += 256) {
        float4 v = bp[i];
        int p = PADI(i);
        sx1[p] = v.x; sy1[p] = v.y; sx2[p] = v.z; sy2[p] = v.w;
    }
    __syncthreads();

    const int wave = t >> 6, lane = t & 63;
    const int row0 = blockIdx.x * 16 + wave * 4;
    const float THI = 0.45f * 1.00002f;
    const float TLO = 0.45f * 0.99998f;

    float ax1[4], ay1[4], ax2[4], ay2[4], areaA[4];
#pragma unroll
    for (int r = 0; r < 4; ++r) {
        int p = PADI(row0 + r);
        ax1[r] = sx1[p]; ay1[r] = sy1[p]; ax2[r] = sx2[p]; ay2[r] = sy2[p];
        areaA[r] = (ax2[r] - ax1[r]) * (ay2[r] - ay1[r]);
    }
    uint32_t w[4] = {0, 0, 0, 0};
#pragma unroll 4
    for (int j = 0; j < 32; ++j) {
        int p = lane * 33 + j;                 // bank (lane+j)%32: 2-way = free
        float bx1 = sx1[p], by1 = sy1[p], bx2 = sx2[p], by2 = sy2[p];
        float areaB = (bx2 - bx1) * (by2 - by1);
#pragma unroll
        for (int r = 0; r < 4; ++r) {
            float ltx = fmaxf(ax1[r], bx1), lty = fmaxf(ay1[r], by1);
            float rbx = fminf(ax2[r], bx2), rby = fminf(ay2[r], by2);
            float ww = fmaxf(rbx - ltx, 0.0f);
            float hh = fmaxf(rby - lty, 0.0f);
            float inter = ww * hh;
            float uni  = (areaA[r] + areaB) - inter;
            float unim = fmaxf(uni, 1e-12f);
            float q1 = inter * __builtin_amdgcn_rcpf(unim);
            bool hi = q1 > THI;
            bool lo = q1 < TLO;
            bool adjb;
            if (__builtin_expect(__any((int)!(hi || lo)), 0))
                adjb = (inter / unim) > NMS_THR;   // exact IEEE div, rare
            else
                adjb = hi;
            if (adjb) w[r] |= (1u << j);
        }
    }
#pragma unroll
    for (int r = 0; r < 4; ++r) {
        int row = row0 + r;
        uint32_t dmask = (lane == (row >> 5)) ? ~(1u << (row & 31)) : 0xFFFFFFFFu;
        adj[((size_t)b * NN + row) * WORDS + lane] = w[r] & dmask;
    }
}

// ---------------- K2: per-(b,c) bitonic sort, 1024 threads ----------------
__device__ __forceinline__ void ce_reg(u64& a, u64& b, bool up) {
    u64 mn = (a < b) ? a : b;
    u64 mx = (a < b) ? b : a;
    a = up ? mx : mn;
    b = up ? mn : mx;
}

__global__ __launch_bounds__(1024) void sort_kernel(const float* __restrict__ conf,
                                                    uint32_t* __restrict__ wsOrd) {
    __shared__ u64 keys[2176];   // KPAD(2047)=2174
    const int bc = blockIdx.x;
    const int t  = threadIdx.x;
    const float* cf = conf + (size_t)bc * NN;

    if (t < 512) {
        const int g = 4 * t;
        float4 v = ((const float4*)cf)[t];
        float f0 = (v.x > PRE_THR) ? v.x : 0.0f;
        float f1 = (v.y > PRE_THR) ? v.y : 0.0f;
        float f2 = (v.z > PRE_THR) ? v.z : 0.0f;
        float f3 = (v.w > PRE_THR) ? v.w : 0.0f;
        u64 a0 = ((u64)__float_as_uint(f0) << 32) | (uint32_t)(NN - 1 - (g + 0));
        u64 a1 = ((u64)__float_as_uint(f1) << 32) | (uint32_t)(NN - 1 - (g + 1));
        u64 a2 = ((u64)__float_as_uint(f2) << 32) | (uint32_t)(NN - 1 - (g + 2));
        u64 a3 = ((u64)__float_as_uint(f3) << 32) | (uint32_t)(NN - 1 - (g + 3));
        ce_reg(a0, a1, true);
        ce_reg(a2, a3, false);
        bool up4 = ((g & 4) == 0);
        ce_reg(a0, a2, up4); ce_reg(a1, a3, up4);
        ce_reg(a0, a1, up4); ce_reg(a2, a3, up4);
        keys[KPAD(g + 0)] = a0; keys[KPAD(g + 1)] = a1;
        keys[KPAD(g + 2)] = a2; keys[KPAD(g + 3)] = a3;
    }
    __syncthreads();

    for (unsigned k = 8; k <= NN; k <<= 1) {
        unsigned j = k >> 1;
        while (j >= 2) {
            const unsigned h = j >> 1;
            if (t < 512) {
                unsigned g  = (((unsigned)t & ~(h - 1)) << 2) | ((unsigned)t & (h - 1));
                bool up = ((g & k) == 0);
                u64 e0 = keys[KPAD(g)];
                u64 e1 = keys[KPAD(g + h)];
                u64 e2 = keys[KPAD(g + j)];
                u64 e3 = keys[KPAD(g + j + h)];
                ce_reg(e0, e2, up); ce_reg(e1, e3, up);
                ce_reg(e0, e1, up); ce_reg(e2, e3, up);
                keys[KPAD(g)]         = e0;
                keys[KPAD(g + h)]     = e1;
                keys[KPAD(g + j)]     = e2;
                keys[KPAD(g + j + h)] = e3;
            }
            __syncthreads();
            j >>= 2;
        }
        if (j == 1) {
            unsigned i  = (unsigned)t << 1;
            bool up = ((i & k) == 0);
            u64 a = keys[KPAD(i)], d = keys[KPAD(i + 1)];
            ce_reg(a, d, up);
            keys[KPAD(i)] = a; keys[KPAD(i + 1)] = d;
            __syncthreads();
        }
    }

    uint32_t* ov = wsOrd + (size_t)bc * NN;
    for (int r = t; r < NN; r += 1024) {
        u64 kk = keys[KPAD(r)];
        uint32_t idx = (uint32_t)(NN - 1) - (uint32_t)(kk & 0xffffffffu);
        uint32_t nz  = ((uint32_t)(kk >> 32) != 0u) ? 0x10000u : 0u;
        ov[r] = idx | nz;
    }
}

// ---------------- K3: rank-space sub-adjacency extraction ----------------
__global__ __launch_bounds__(256) void extract_kernel(const uint32_t* __restrict__ adj,
                                                      const uint32_t* __restrict__ wsOrd,
                                                      uint32_t* __restrict__ wsM) {
    const int blkid = blockIdx.x;
    const int bc = blkid >> 3, chunk = blkid & 7;
    const int b  = bc >> 5;
    const int t = threadIdx.x, wv = t >> 6, lane = t & 63, e = lane & 31, h = lane >> 5;
    const uint32_t* ov = wsOrd + (size_t)bc * NN;
    const uint32_t* ab = adj + (size_t)b * NN * WORDS;

    for (int blk = chunk * 8 + wv; blk < chunk * 8 + 8; blk += 4) {
        uint32_t ue = ov[blk * 32 + e];
        int widx = (int)((ue & 0xffffu) >> 5);
        int bpos = (int)(ue & 31u);
        uint32_t wb[16];
#pragma unroll
        for (int k = 0; k < 16; ++k) {
            uint32_t ud = ov[blk * 32 + k * 2 + h] & 0xffffu;
            wb[k] = ab[(size_t)ud * WORDS + widx];
        }
        uint32_t vM = 0;
#pragma unroll
        for (int k = 0; k < 16; ++k) {
            unsigned long long bal = __ballot(((wb[k] >> bpos) & 1u) != 0u);
            vM = (lane == 2 * k    ) ? (uint32_t)bal         : vM;
            vM = (lane == 2 * k + 1) ? (uint32_t)(bal >> 32) : vM;
        }
        if (lane < 32)
            wsM[(size_t)bc * NN + blk * 32 + lane] = vM & (0xFFFFFFFEu << lane);
    }
}

// ---------------- K4: sparse serial scan (survivor-only loads) ----------------
// One wave per (b,c). Per block: 1 bpermute + ballot -> alive0 (32 ranks tested
// at once). Dead blocks: ~10 instructions, zero loads. Active: ff1-loop resolve
// (iterations = within-block survivors, ~3 avg) + survivor-row loads only,
// grouped 4-wide with idempotent padding (OR of a repeated row is a no-op).
__global__ __launch_bounds__(64, 1) void scan_kernel(const float* __restrict__ conf,
                                                     const uint32_t* __restrict__ adj,
                                                     const uint32_t* __restrict__ wsOrd,
                                                     const uint32_t* __restrict__ wsM,
                                                     float* __restrict__ out) {
    __shared__ uint32_t ordL[NN];   // 8 KB
    __shared__ uint32_t Ml[NN];     // 8 KB (pre-masked M')
    __shared__ uint32_t Sarr[WORDS];
    const int bc = blockIdx.x;
    const int b  = bc >> 5;
    const int lane = threadIdx.x;
    const int lane31 = lane & 31;
    const uint32_t* ov = wsOrd + (size_t)bc * NN;
    const uint32_t* mv = wsM   + (size_t)bc * NN;
    const uint32_t* const rowp = adj + (size_t)b * NN * WORDS + lane;
    const float* cf = conf + (size_t)bc * NN;
    float* op = out + (size_t)bc * NN;

    // Stage ord + M into LDS (uint4-wide, coalesced).
    for (int i = lane; i < NN / 4; i += 64) {
        ((uint4*)ordL)[i] = ((const uint4*)ov)[i];
        ((uint4*)Ml)[i]   = ((const uint4*)mv)[i];
    }
    __syncthreads();

    uint32_t S = 0;
    uint32_t u = ordL[lane31];
    uint32_t m = Ml[lane31];

    for (int k = 0; k < NBLK; ++k) {
        // prefetch next block's u/m (issued before the bpermute on the chain)
        int kn = (k + 1 > 63) ? 63 : k + 1;
        uint32_t uN = ordL[kn * 32 + lane31];
        uint32_t mN = Ml[kn * 32 + lane31];

        int pm = __builtin_amdgcn_ds_bpermute(
            (int)(((u & 0xffffu) >> 5) << 2), (int)S);
        bool a0 = (((u >> 16) & 1u) != 0u) && (((pm >> (u & 31u)) & 1) == 0);
        uint32_t alive = (uint32_t)__ballot((int)a0);

        if (alive) {
            // ---- resolve: ff1 loop, iterations = within-block survivors ----
            uint32_t work = alive, surv = 0;
            while (work) {
                int d = __builtin_ctz(work);
                surv |= (1u << d);
                uint32_t md = (uint32_t)__builtin_amdgcn_readlane((int)m, d);
                work &= ~(md | (1u << d));     // md pre-masked to later ranks
            }
            // ---- OR survivor rows, 4 loads per group (padded, idempotent) ----
            uint32_t w2 = surv;
            while (w2) {
                int d0 = __builtin_ctz(w2); w2 &= w2 - 1;
                int d1 = w2 ? __builtin_ctz(w2) : d0; if (w2) w2 &= w2 - 1;
                int d2 = w2 ? __builtin_ctz(w2) : d0; if (w2) w2 &= w2 - 1;
                int d3 = w2 ? __builtin_ctz(w2) : d0; if (w2) w2 &= w2 - 1;
                int i0 = __builtin_amdgcn_readlane((int)u, d0) & 0xffff;
                int i1 = __builtin_amdgcn_readlane((int)u, d1) & 0xffff;
                int i2 = __builtin_amdgcn_readlane((int)u, d2) & 0xffff;
                int i3 = __builtin_amdgcn_readlane((int)u, d3) & 0xffff;
                uint32_t r0 = rowp[(size_t)i0 * WORDS];
                uint32_t r1 = rowp[(size_t)i1 * WORDS];
                uint32_t r2 = rowp[(size_t)i2 * WORDS];
                uint32_t r3 = rowp[(size_t)i3 * WORDS];
                S |= (r0 | r1) | (r2 | r3);
            }
        }
        u = uN; m = mN;
    }

    Sarr[lane] = S;
    __syncthreads();

    // Output: float4 per lane per iter, sup bits from Sarr.
#pragma unroll
    for (int it = 0; it < 8; ++it) {
        int i4 = it * 256 + lane * 4;
        float4 v = ((const float4*)cf)[it * 64 + lane];
        uint32_t sw = Sarr[i4 >> 5];
        float4 o;
        o.x = (v.x > PRE_THR && !((sw >> ((i4 + 0) & 31)) & 1u)) ? v.x : 0.0f;
        o.y = (v.y > PRE_THR && !((sw >> ((i4 + 1) & 31)) & 1u)) ? v.y : 0.0f;
        o.z = (v.z > PRE_THR && !((sw >> ((i4 + 2) & 31)) & 1u)) ? v.z : 0.0f;
        o.w = (v.w > PRE_THR && !((sw >> ((i4 + 3) & 31)) & 1u)) ? v.w : 0.0f;
        ((float4*)op)[it * 64 + lane] = o;
    }
}

// ---------------- Fallback (ws too small): monolithic ----------------
__global__ __launch_bounds__(256) void nms_fallback(const float* __restrict__ conf,
                                                    const uint32_t* __restrict__ adj,
                                                    float* __restrict__ out) {
    __shared__ unsigned long long keys[NN];
    __shared__ uint32_t ordv[NN];
    __shared__ uint32_t Mlds[NBLK * 32];
    __shared__ uint32_t Sarr[WORDS];
    const int bc = blockIdx.x;
    const int b  = bc >> 5;
    const int t  = threadIdx.x;
    const float* cf = conf + (size_t)bc * NN;
    const uint32_t* const abase = adj + (size_t)b * NN * WORDS;

    for (int i = t; i < NN; i += 256) {
        float v  = cf[i];
        float vt = (v > PRE_THR) ? v : 0.0f;
        keys[i] = ((unsigned long long)__float_as_uint(vt) << 32) | (uint32_t)(NN - 1 - i);
    }
    __syncthreads();
    for (unsigned k = 2; k <= NN; k <<= 1)
        for (unsigned j = k >> 1; j > 0; j >>= 1) {
            for (unsigned p = t; p < NN / 2; p += 256) {
                unsigned i  = ((p & ~(j - 1)) << 1) | (p & (j - 1));
                unsigned ij = i | j;
                unsigned long long a = keys[i], d = keys[ij];
                bool up = ((i & k) == 0);
                if (up ? (a < d) : (a > d)) { keys[i] = d; keys[ij] = a; }
            }
            __syncthreads();
        }
    for (int r = t; r < NN; r += 256) {
        unsigned long long kk = keys[r];
        uint32_t idx = (uint32_t)(NN - 1) - (uint32_t)(kk & 0xffffffffu);
        uint32_t nz  = ((uint32_t)(kk >> 32) != 0u) ? 0x10000u : 0u;
        ordv[r] = idx | nz;
    }
    __syncthreads();
    {
        const int wid = t >> 6, lane = t & 63, e = lane & 31, h = lane >> 5;
        for (int blk = wid * 16; blk < wid * 16 + 16; ++blk) {
            uint32_t ue = ordv[blk * 32 + e];
            int widx = (int)((ue & 0xffffu) >> 5);
            int bpos = (int)(ue & 31u);
            uint32_t vM = 0;
#pragma unroll
            for (int half = 0; half < 2; ++half) {
                uint32_t wbuf[8];
#pragma unroll
                for (int k = 0; k < 8; ++k) {
                    int d = half * 16 + k * 2 + h;
                    uint32_t ud = ordv[blk * 32 + d] & 0xffffu;
                    wbuf[k] = abase[(size_t)ud * WORDS + widx];
                }
#pragma unroll
                for (int k = 0; k < 8; ++k) {
                    int d0 = half * 16 + k * 2;
                    unsigned long long bal = __ballot(((wbuf[k] >> bpos) & 1u) != 0u);
                    vM = (lane == d0    ) ? (uint32_t)bal         : vM;
                    vM = (lane == d0 + 1) ? (uint32_t)(bal >> 32) : vM;
                }
            }
            if (lane < 32) Mlds[blk * 32 + lane] = vM;
        }
    }
    __syncthreads();
    if (t < 64) {
        const int lane = t;
        const uint32_t* const rowp = abase + lane;
        uint32_t S = 0;
        uint32_t rbA[32], rbB[32];
        uint32_t u_c, m_c, u_n, m_n;
        u_c = ordv[lane & 31];
        m_c = Mlds[lane & 31];
#pragma unroll
        for (int d = 0; d < 32; ++d) {
            int ud = __builtin_amdgcn_readlane((int)u_c, d) & 0xffff;
            rbA[d] = rowp[(size_t)ud * WORDS];
        }
        auto do_block = [&](int blk, uint32_t (&rbC)[32], uint32_t (&rbN)[32]) {
            u_n = 0; m_n = 0;
            if (blk < 63) {
                u_n = ordv[(blk + 1) * 32 + (lane & 31)];
                m_n = Mlds[(blk + 1) * 32 + (lane & 31)];
#pragma unroll
                for (int d = 0; d < 32; ++d) {
                    int ud = __builtin_amdgcn_readlane((int)u_n, d) & 0xffff;
                    rbN[d] = rowp[(size_t)ud * WORDS];
                }
            }
            int wq  = (int)(((u_c & 0xffffu) >> 5) << 2);
            int bpv = (int)(u_c & 31u);
            int pm  = __builtin_amdgcn_ds_bpermute(wq, (int)S);
            bool a0 = (((u_c >> 16) & 1u) != 0u) && (((pm >> bpv) & 1) == 0);
            uint32_t alive = (uint32_t)__ballot((int)a0);
#pragma unroll
            for (int d = 0; d < 32; ++d) {
                uint32_t rowd = (uint32_t)__builtin_amdgcn_readlane((int)m_c, d);
                uint32_t mk = rowd & (0xFFFFFFFEu << d);
                alive = (alive & (1u << d)) ? (alive & ~mk) : alive;
            }
            uint32_t acc = 0;
#pragma unroll
            for (int d = 0; d < 32; ++d)
                acc |= (alive & (1u << d)) ? rbC[d] : 0u;
            S |= acc;
            u_c = u_n; m_c = m_n;
        };
        for (int blk = 0; blk < 64; blk += 2) {
            do_block(blk,     rbA, rbB);
            do_block(blk + 1, rbB, rbA);
        }
        Sarr[lane] = S;
    }
    __syncthreads();
    float* op = out + (size_t)bc * NN;
    for (int i = t; i < NN; i += 256) {
        float v = cf[i];
        bool sup = (Sarr[i >> 5] >> (i & 31)) & 1u;
        op[i] = (v > PRE_THR && !sup) ? v : 0.0f;
    }
}

extern "C" void kernel_launch(void* const* d_in, const int* in_sizes, int n_in,
                              void* d_out, int out_size, void* d_ws, size_t ws_size,
                              hipStream_t stream) {
    const float* bbs  = (const float*)d_in[0];   // [8,2048,4]
    const float* conf = (const float*)d_in[1];   // [8,32,2048]
    float* out = (float*)d_out;                  // [8,32,2048]

    const size_t adjB = (size_t)BB * NN * WORDS * sizeof(uint32_t);   // 4 MB
    const size_t ordB = (size_t)BB * CC * NN * sizeof(uint32_t);      // 2 MB
    const size_t mB   = ordB;                                          // 2 MB
    uint32_t* adj = (uint32_t*)d_ws;

    if (ws_size >= adjB + ordB + mB) {
        uint32_t* wsOrd = (uint32_t*)((char*)d_ws + adjB);
        uint32_t* wsM   = (uint32_t*)((char*)d_ws + adjB + ordB);
        adj_kernel    <<<dim3(NN / 16, BB), 256, 0, stream>>>(bbs, adj);
        sort_kernel   <<<BB * CC, 1024, 0, stream>>>(conf, wsOrd);
        extract_kernel<<<BB * CC * 8, 256, 0, stream>>>(adj, wsOrd, wsM);
        scan_kernel   <<<BB * CC, 64, 0, stream>>>(conf, adj, wsOrd, wsM, out);
    } else if (ws_size >= adjB) {
        adj_kernel  <<<dim3(NN / 16, BB), 256, 0, stream>>>(bbs, adj);
        nms_fallback<<<BB * CC, 256, 0, stream>>>(conf, adj, out);
    }
}

// Round 12
// 165.799 us; speedup vs baseline: 1.6778x; 1.6010x over previous
//
#include <hip/hip_runtime.h>
#include <stdint.h>

// Keep IoU arithmetic bit-identical to an IEEE no-FMA reference:
#pragma clang fp contract(off)

#define BB   8
#define NN   2048
#define CC   32
#define WORDS 64           // uint32 words per 2048-bit row mask
#define NBLK 64            // rank blocks of 32
#define NMS_THR 0.45f
#define PRE_THR 0.005f
#define PADI(i) ((((i) >> 5) * 33) + ((i) & 31))   // padded SoA index
#define KPAD(i) ((i) + ((i) >> 4))                 // u64 key pad

typedef unsigned long long u64;

// ---------------- K1: per-image adjacency bitmask ----------------
// Branch-free exact threshold test:
//   RN32(inter/unim) > 0.45f  <=>  (double)inter > M * (double)unim,
//   M = (double)0.45f + 2^-26 (half-ulp above T; tie rounds-to-even to T since
//   T's mantissa 0x666666 is even; M*unim is a <=50-bit product -> exact f64).
// No rcp, no div, no divergent branches -> straight-line unrollable j-loop.
__global__ __launch_bounds__(256) void adj_kernel(const float* __restrict__ bbs,
                                                  uint32_t* __restrict__ adj) {
    __shared__ float2 sA[2112];   // (x1,y1), stride-33 pad: b64 banks 2-way = free
    __shared__ float2 sB[2112];   // (x2,y2)
    const int b = blockIdx.y;
    const int t = threadIdx.x;
    const float4* bp = (const float4*)bbs + (size_t)b * NN;
    for (int i = t; i < NN; i += 256) {
        float4 v = bp[i];
        int p = PADI(i);
        sA[p] = make_float2(v.x, v.y);
        sB[p] = make_float2(v.z, v.w);
    }
    __syncthreads();

    const int wave = t >> 6, lane = t & 63;
    const int row0 = blockIdx.x * 16 + wave * 4;
    const double M = (double)0.45f + 0x1p-26;

    float ax1[4], ay1[4], ax2[4], ay2[4], areaA[4];
#pragma unroll
    for (int r = 0; r < 4; ++r) {
        int p = PADI(row0 + r);                 // wave-uniform broadcast reads
        float2 a = sA[p], bz = sB[p];
        ax1[r] = a.x; ay1[r] = a.y; ax2[r] = bz.x; ay2[r] = bz.y;
        areaA[r] = (bz.x - a.x) * (bz.y - a.y);
    }
    uint32_t w[4] = {0, 0, 0, 0};
#pragma unroll
    for (int j = 0; j < 32; ++j) {
        int p = lane * 33 + j;                  // bank 2*(lane+...)%32: 2-way free
        float2 a = sA[p], bz = sB[p];
        float areaB = (bz.x - a.x) * (bz.y - a.y);
#pragma unroll
        for (int r = 0; r < 4; ++r) {
            float ltx = fmaxf(ax1[r], a.x),  lty = fmaxf(ay1[r], a.y);
            float rbx = fminf(ax2[r], bz.x), rby = fminf(ay2[r], bz.y);
            float ww = fmaxf(rbx - ltx, 0.0f);
            float hh = fmaxf(rby - lty, 0.0f);
            float inter = ww * hh;
            float uni  = (areaA[r] + areaB) - inter;
            float unim = fmaxf(uni, 1e-12f);
            bool adjb = (double)inter > M * (double)unim;   // exact, branch-free
            w[r] |= adjb ? (1u << j) : 0u;
        }
    }
#pragma unroll
    for (int r = 0; r < 4; ++r) {
        int row = row0 + r;
        uint32_t dmask = (lane == (row >> 5)) ? ~(1u << (row & 31)) : 0xFFFFFFFFu;
        adj[((size_t)b * NN + row) * WORDS + lane] = w[r] & dmask;
    }
}

// ---------------- K2: per-(b,c) bitonic sort, 1024 threads ----------------
__device__ __forceinline__ void ce_reg(u64& a, u64& b, bool up) {
    u64 mn = (a < b) ? a : b;
    u64 mx = (a < b) ? b : a;
    a = up ? mx : mn;
    b = up ? mn : mx;
}

__global__ __launch_bounds__(1024) void sort_kernel(const float* __restrict__ conf,
                                                    uint32_t* __restrict__ wsOrd) {
    __shared__ u64 keys[2176];   // KPAD(2047)=2174
    const int bc = blockIdx.x;
    const int t  = threadIdx.x;
    const float* cf = conf + (size_t)bc * NN;

    if (t < 512) {
        const int g = 4 * t;
        float4 v = ((const float4*)cf)[t];
        float f0 = (v.x > PRE_THR) ? v.x : 0.0f;
        float f1 = (v.y > PRE_THR) ? v.y : 0.0f;
        float f2 = (v.z > PRE_THR) ? v.z : 0.0f;
        float f3 = (v.w > PRE_THR) ? v.w : 0.0f;
        u64 a0 = ((u64)__float_as_uint(f0) << 32) | (uint32_t)(NN - 1 - (g + 0));
        u64 a1 = ((u64)__float_as_uint(f1) << 32) | (uint32_t)(NN - 1 - (g + 1));
        u64 a2 = ((u64)__float_as_uint(f2) << 32) | (uint32_t)(NN - 1 - (g + 2));
        u64 a3 = ((u64)__float_as_uint(f3) << 32) | (uint32_t)(NN - 1 - (g + 3));
        ce_reg(a0, a1, true);
        ce_reg(a2, a3, false);
        bool up4 = ((g & 4) == 0);
        ce_reg(a0, a2, up4); ce_reg(a1, a3, up4);
        ce_reg(a0, a1, up4); ce_reg(a2, a3, up4);
        keys[KPAD(g + 0)] = a0; keys[KPAD(g + 1)] = a1;
        keys[KPAD(g + 2)] = a2; keys[KPAD(g + 3)] = a3;
    }
    __syncthreads();

    for (unsigned k = 8; k <= NN; k <<= 1) {
        unsigned j = k >> 1;
        while (j >= 2) {
            const unsigned h = j >> 1;
            if (t < 512) {
                unsigned g  = (((unsigned)t & ~(h - 1)) << 2) | ((unsigned)t & (h - 1));
                bool up = ((g & k) == 0);
                u64 e0 = keys[KPAD(g)];
                u64 e1 = keys[KPAD(g + h)];
                u64 e2 = keys[KPAD(g + j)];
                u64 e3 = keys[KPAD(g + j + h)];
                ce_reg(e0, e2, up); ce_reg(e1, e3, up);
                ce_reg(e0, e1, up); ce_reg(e2, e3, up);
                keys[KPAD(g)]         = e0;
                keys[KPAD(g + h)]     = e1;
                keys[KPAD(g + j)]     = e2;
                keys[KPAD(g + j + h)] = e3;
            }
            __syncthreads();
            j >>= 2;
        }
        if (j == 1) {
            unsigned i  = (unsigned)t << 1;
            bool up = ((i & k) == 0);
            u64 a = keys[KPAD(i)], d = keys[KPAD(i + 1)];
            ce_reg(a, d, up);
            keys[KPAD(i)] = a; keys[KPAD(i + 1)] = d;
            __syncthreads();
        }
    }

    uint32_t* ov = wsOrd + (size_t)bc * NN;
    for (int r = t; r < NN; r += 1024) {
        u64 kk = keys[KPAD(r)];
        uint32_t idx = (uint32_t)(NN - 1) - (uint32_t)(kk & 0xffffffffu);
        uint32_t nz  = ((uint32_t)(kk >> 32) != 0u) ? 0x10000u : 0u;
        ov[r] = idx | nz;
    }
}

// ---------------- K3: rank-space sub-adjacency extraction ----------------
__global__ __launch_bounds__(256) void extract_kernel(const uint32_t* __restrict__ adj,
                                                      const uint32_t* __restrict__ wsOrd,
                                                      uint32_t* __restrict__ wsM) {
    const int blkid = blockIdx.x;
    const int bc = blkid >> 3, chunk = blkid & 7;
    const int b  = bc >> 5;
    const int t = threadIdx.x, wv = t >> 6, lane = t & 63, e = lane & 31, h = lane >> 5;
    const uint32_t* ov = wsOrd + (size_t)bc * NN;
    const uint32_t* ab = adj + (size_t)b * NN * WORDS;

    for (int blk = chunk * 8 + wv; blk < chunk * 8 + 8; blk += 4) {
        uint32_t ue = ov[blk * 32 + e];
        int widx = (int)((ue & 0xffffu) >> 5);
        int bpos = (int)(ue & 31u);
        uint32_t wb[16];
#pragma unroll
        for (int k = 0; k < 16; ++k) {
            uint32_t ud = ov[blk * 32 + k * 2 + h] & 0xffffu;
            wb[k] = ab[(size_t)ud * WORDS + widx];
        }
        uint32_t vM = 0;
#pragma unroll
        for (int k = 0; k < 16; ++k) {
            unsigned long long bal = __ballot(((wb[k] >> bpos) & 1u) != 0u);
            vM = (lane == 2 * k    ) ? (uint32_t)bal         : vM;
            vM = (lane == 2 * k + 1) ? (uint32_t)(bal >> 32) : vM;
        }
        if (lane < 32)
            wsM[(size_t)bc * NN + blk * 32 + lane] = vM & (0xFFFFFFFEu << lane);
    }
}

// ---------------- K4: producer/consumer serial scan + output (R6-proven) ----------------
__global__ __launch_bounds__(256) void scan_kernel(const float* __restrict__ conf,
                                                   const uint32_t* __restrict__ adj,
                                                   const uint32_t* __restrict__ wsOrd,
                                                   const uint32_t* __restrict__ wsM,
                                                   float* __restrict__ out) {
    __shared__ uint32_t buf[2][256][64];   // 128 KB: 2 x (8 blocks x 32 rows x 64 words)
    __shared__ uint32_t ordL[NN];          // 8 KB
    __shared__ uint32_t Ml[NN];            // 8 KB (pre-masked M')
    __shared__ uint32_t Sarr[WORDS];
    const int bc = blockIdx.x;
    const int b  = bc >> 5;
    const int t  = threadIdx.x, wid = t >> 6, lane = t & 63;
    const uint32_t* ov = wsOrd + (size_t)bc * NN;
    const uint32_t* mv = wsM   + (size_t)bc * NN;
    const uint32_t* ab = adj + (size_t)b * NN * WORDS;
    const float* cf = conf + (size_t)bc * NN;
    float* op = out + (size_t)bc * NN;

    for (int i = t; i < NN; i += 256) { ordL[i] = ov[i]; Ml[i] = mv[i]; }
    __syncthreads();

    // Fill chunk 0 (all 4 waves; row r covered by wave r%4).
    for (int r = wid; r < 256; r += 4) {
        uint32_t ud = ordL[r] & 0xffffu;               // wave-uniform broadcast read
        buf[0][r][lane] = ab[(size_t)ud * WORDS + lane];   // 256B coalesced
    }
    __syncthreads();

    uint32_t S = 0;
    for (int c = 0; c < 8; ++c) {
        const int cb = c & 1, nb = cb ^ 1;
        if (wid != 0) {
            // ---- producers: stream chunk c+1 ----
            if (c < 7) {
                const int base = (c + 1) * 256;
                for (int r = wid - 1; r < 256; r += 3) {
                    uint32_t ud = ordL[base + r] & 0xffffu;
                    buf[nb][r][lane] = ab[(size_t)ud * WORDS + lane];
                }
            }
        } else {
            // ---- consumer: serial resolve of chunk c's 8 blocks ----
            for (int k = 0; k < 8; ++k) {
                const int blk = c * 8 + k;
                uint32_t u = ordL[blk * 32 + (lane & 31)];
                uint32_t m = Ml[blk * 32 + (lane & 31)];
                int wq = (int)(((u & 0xffffu) >> 5) << 2);
                int pm = __builtin_amdgcn_ds_bpermute(wq, (int)S);
                uint32_t rw[32];
#pragma unroll
                for (int d = 0; d < 32; ++d)
                    rw[d] = buf[cb][k * 32 + d][lane];  // bank=lane%32, 2-way free
                bool a0 = (((u >> 16) & 1u) != 0u) && (((pm >> (u & 31u)) & 1) == 0);
                uint32_t alive = (uint32_t)__ballot((int)a0);
                if (alive) {
#pragma unroll
                    for (int d = 0; d < 32; ++d) {
                        uint32_t mk = (uint32_t)__builtin_amdgcn_readlane((int)m, d);
                        alive = (alive & (1u << d)) ? (alive & ~mk) : alive;
                    }
                    uint32_t acc = 0;
#pragma unroll
                    for (int d = 0; d < 32; ++d)
                        acc |= (alive & (1u << d)) ? rw[d] : 0u;
                    S |= acc;
                }
            }
        }
        __syncthreads();
    }
    if (wid == 0) Sarr[lane] = S;
    __syncthreads();

#pragma unroll 2
    for (int i = t; i < NN; i += 256) {
        float v = cf[i];
        bool sup = (Sarr[i >> 5] >> (i & 31)) & 1u;
        op[i] = (v > PRE_THR && !sup) ? v : 0.0f;
    }
}

// ---------------- Fallback (ws too small): monolithic ----------------
__global__ __launch_bounds__(256) void nms_fallback(const float* __restrict__ conf,
                                                    const uint32_t* __restrict__ adj,
                                                    float* __restrict__ out) {
    __shared__ unsigned long long keys[NN];
    __shared__ uint32_t ordv[NN];
    __shared__ uint32_t Mlds[NBLK * 32];
    __shared__ uint32_t Sarr[WORDS];
    const int bc = blockIdx.x;
    const int b  = bc >> 5;
    const int t  = threadIdx.x;
    const float* cf = conf + (size_t)bc * NN;
    const uint32_t* const abase = adj + (size_t)b * NN * WORDS;

    for (int i = t; i < NN; i += 256) {
        float v  = cf[i];
        float vt = (v > PRE_THR) ? v : 0.0f;
        keys[i] = ((unsigned long long)__float_as_uint(vt) << 32) | (uint32_t)(NN - 1 - i);
    }
    __syncthreads();
    for (unsigned k = 2; k <= NN; k <<= 1)
        for (unsigned j = k >> 1; j > 0; j >>= 1) {
            for (unsigned p = t; p < NN / 2; p += 256) {
                unsigned i  = ((p & ~(j - 1)) << 1) | (p & (j - 1));
                unsigned ij = i | j;
                unsigned long long a = keys[i], d = keys[ij];
                bool up = ((i & k) == 0);
                if (up ? (a < d) : (a > d)) { keys[i] = d; keys[ij] = a; }
            }
            __syncthreads();
        }
    for (int r = t; r < NN; r += 256) {
        unsigned long long kk = keys[r];
        uint32_t idx = (uint32_t)(NN - 1) - (uint32_t)(kk & 0xffffffffu);
        uint32_t nz  = ((uint32_t)(kk >> 32) != 0u) ? 0x10000u : 0u;
        ordv[r] = idx | nz;
    }
    __syncthreads();
    {
        const int wid = t >> 6, lane = t & 63, e = lane & 31, h = lane >> 5;
        for (int blk = wid * 16; blk < wid * 16 + 16; ++blk) {
            uint32_t ue = ordv[blk * 32 + e];
            int widx = (int)((ue & 0xffffu) >> 5);
            int bpos = (int)(ue & 31u);
            uint32_t vM = 0;
#pragma unroll
            for (int half = 0; half < 2; ++half) {
                uint32_t wbuf[8];
#pragma unroll
                for (int k = 0; k < 8; ++k) {
                    int d = half * 16 + k * 2 + h;
                    uint32_t ud = ordv[blk * 32 + d] & 0xffffu;
                    wbuf[k] = abase[(size_t)ud * WORDS + widx];
                }
#pragma unroll
                for (int k = 0; k < 8; ++k) {
                    int d0 = half * 16 + k * 2;
                    unsigned long long bal = __ballot(((wbuf[k] >> bpos) & 1u) != 0u);
                    vM = (lane == d0    ) ? (uint32_t)bal         : vM;
                    vM = (lane == d0 + 1) ? (uint32_t)(bal >> 32) : vM;
                }
            }
            if (lane < 32) Mlds[blk * 32 + lane] = vM;
        }
    }
    __syncthreads();
    if (t < 64) {
        const int lane = t;
        const uint32_t* const rowp = abase + lane;
        uint32_t S = 0;
        uint32_t rbA[32], rbB[32];
        uint32_t u_c, m_c, u_n, m_n;
        u_c = ordv[lane & 31];
        m_c = Mlds[lane & 31];
#pragma unroll
        for (int d = 0; d < 32; ++d) {
            int ud = __builtin_amdgcn_readlane((int)u_c, d) & 0xffff;
            rbA[d] = rowp[(size_t)ud * WORDS];
        }
        auto do_block = [&](int blk, uint32_t (&rbC)[32], uint32_t (&rbN)[32]) {
            u_n = 0; m_n = 0;
            if (blk < 63) {
                u_n = ordv[(blk + 1) * 32 + (lane & 31)];
                m_n = Mlds[(blk + 1) * 32 + (lane & 31)];
#pragma unroll
                for (int d = 0; d < 32; ++d) {
                    int ud = __builtin_amdgcn_readlane((int)u_n, d) & 0xffff;
                    rbN[d] = rowp[(size_t)ud * WORDS];
                }
            }
            int wq  = (int)(((u_c & 0xffffu) >> 5) << 2);
            int bpv = (int)(u_c & 31u);
            int pm  = __builtin_amdgcn_ds_bpermute(wq, (int)S);
            bool a0 = (((u_c >> 16) & 1u) != 0u) && (((pm >> bpv) & 1) == 0);
            uint32_t alive = (uint32_t)__ballot((int)a0);
#pragma unroll
            for (int d = 0; d < 32; ++d) {
                uint32_t rowd = (uint32_t)__builtin_amdgcn_readlane((int)m_c, d);
                uint32_t mk = rowd & (0xFFFFFFFEu << d);
                alive = (alive & (1u << d)) ? (alive & ~mk) : alive;
            }
            uint32_t acc = 0;
#pragma unroll
            for (int d = 0; d < 32; ++d)
                acc |= (alive & (1u << d)) ? rbC[d] : 0u;
            S |= acc;
            u_c = u_n; m_c = m_n;
        };
        for (int blk = 0; blk < 64; blk += 2) {
            do_block(blk,     rbA, rbB);
            do_block(blk + 1, rbB, rbA);
        }
        Sarr[lane] = S;
    }
    __syncthreads();
    float* op = out + (size_t)bc * NN;
    for (int i = t; i < NN; i += 256) {
        float v = cf[i];
        bool sup = (Sarr[i >> 5] >> (i & 31)) & 1u;
        op[i] = (v > PRE_THR && !sup) ? v : 0.0f;
    }
}

extern "C" void kernel_launch(void* const* d_in, const int* in_sizes, int n_in,
                              void* d_out, int out_size, void* d_ws, size_t ws_size,
                              hipStream_t stream) {
    const float* bbs  = (const float*)d_in[0];   // [8,2048,4]
    const float* conf = (const float*)d_in[1];   // [8,32,2048]
    float* out = (float*)d_out;                  // [8,32,2048]

    const size_t adjB = (size_t)BB * NN * WORDS * sizeof(uint32_t);   // 4 MB
    const size_t ordB = (size_t)BB * CC * NN * sizeof(uint32_t);      // 2 MB
    const size_t mB   = ordB;                                          // 2 MB
    uint32_t* adj = (uint32_t*)d_ws;

    if (ws_size >= adjB + ordB + mB) {
        uint32_t* wsOrd = (uint32_t*)((char*)d_ws + adjB);
        uint32_t* wsM   = (uint32_t*)((char*)d_ws + adjB + ordB);
        adj_kernel    <<<dim3(NN / 16, BB), 256, 0, stream>>>(bbs, adj);
        sort_kernel   <<<BB * CC, 1024, 0, stream>>>(conf, wsOrd);
        extract_kernel<<<BB * CC * 8, 256, 0, stream>>>(adj, wsOrd, wsM);
        scan_kernel   <<<BB * CC, 256, 0, stream>>>(conf, adj, wsOrd, wsM, out);
    } else if (ws_size >= adjB) {
        adj_kernel  <<<dim3(NN / 16, BB), 256, 0, stream>>>(bbs, adj);
        nms_fallback<<<BB * CC, 256, 0, stream>>>(conf, adj, out);
    }
}

// Round 13
// 156.722 us; speedup vs baseline: 1.7749x; 1.0579x over previous
//
#include <hip/hip_runtime.h>
#include <stdint.h>

// Keep IoU arithmetic bit-identical to an IEEE no-FMA reference:
#pragma clang fp contract(off)

#define BB   8
#define NN   2048
#define CC   32
#define WORDS 64           // uint32 words per 2048-bit row mask
#define NBLK 64            // rank blocks of 32
#define NMS_THR 0.45f
#define PRE_THR 0.005f
#define PADI(i) ((((i) >> 5) * 33) + ((i) & 31))   // padded SoA index
#define KPAD(i) ((i) + ((i) >> 4))                 // u64 key pad

typedef unsigned long long u64;

// ---------------- K1: per-image adjacency bitmask (R12-proven) ----------------
// Branch-free exact threshold test: RN32(inter/unim) > 0.45f <=> inter > M*unim
// in f64, M = (double)0.45f + 2^-26 (tie rounds-to-even onto 0.45f, whose
// mantissa is even; the product has <=50 significant bits -> exact).
__global__ __launch_bounds__(256) void adj_kernel(const float* __restrict__ bbs,
                                                  uint32_t* __restrict__ adj) {
    __shared__ float2 sA[2112];   // (x1,y1), stride-33 pad
    __shared__ float2 sB[2112];   // (x2,y2)
    const int b = blockIdx.y;
    const int t = threadIdx.x;
    const float4* bp = (const float4*)bbs + (size_t)b * NN;
    for (int i = t; i < NN; i += 256) {
        float4 v = bp[i];
        int p = PADI(i);
        sA[p] = make_float2(v.x, v.y);
        sB[p] = make_float2(v.z, v.w);
    }
    __syncthreads();

    const int wave = t >> 6, lane = t & 63;
    const int row0 = blockIdx.x * 16 + wave * 4;
    const double M = (double)0.45f + 0x1p-26;

    float ax1[4], ay1[4], ax2[4], ay2[4], areaA[4];
#pragma unroll
    for (int r = 0; r < 4; ++r) {
        int p = PADI(row0 + r);                 // wave-uniform broadcast reads
        float2 a = sA[p], bz = sB[p];
        ax1[r] = a.x; ay1[r] = a.y; ax2[r] = bz.x; ay2[r] = bz.y;
        areaA[r] = (bz.x - a.x) * (bz.y - a.y);
    }
    uint32_t w[4] = {0, 0, 0, 0};
#pragma unroll
    for (int j = 0; j < 32; ++j) {
        int p = lane * 33 + j;
        float2 a = sA[p], bz = sB[p];
        float areaB = (bz.x - a.x) * (bz.y - a.y);
#pragma unroll
        for (int r = 0; r < 4; ++r) {
            float ltx = fmaxf(ax1[r], a.x),  lty = fmaxf(ay1[r], a.y);
            float rbx = fminf(ax2[r], bz.x), rby = fminf(ay2[r], bz.y);
            float ww = fmaxf(rbx - ltx, 0.0f);
            float hh = fmaxf(rby - lty, 0.0f);
            float inter = ww * hh;
            float uni  = (areaA[r] + areaB) - inter;
            float unim = fmaxf(uni, 1e-12f);
            bool adjb = (double)inter > M * (double)unim;   // exact, branch-free
            w[r] |= adjb ? (1u << j) : 0u;
        }
    }
#pragma unroll
    for (int r = 0; r < 4; ++r) {
        int row = row0 + r;
        uint32_t dmask = (lane == (row >> 5)) ? ~(1u << (row & 31)) : 0xFFFFFFFFu;
        adj[((size_t)b * NN + row) * WORDS + lane] = w[r] & dmask;
    }
}

// ---------------- K2: fused sort + extract + scan + output ----------------
// One block of 512 threads per (b,c). Phases (barrier-separated):
//   A: fused-pair bitonic sort of (conf<<32|revidx) keys in LDS (R5 structure;
//      512 threads = exactly its working set, no idle waves).
//   B: rank-space sub-adjacency extraction, ordL/Ml kept entirely in LDS
//      (wsOrd/wsM global round-trips eliminated).
//   C: producer/consumer serial greedy scan (R6-proven): wave 0 resolves,
//      waves 1-7 stream adjacency rows into a 128 KB LDS double buffer.
//   D: filtered output write.
// keys[] LDS-aliases the scan row buffer (disjoint phases).
__device__ __forceinline__ void ce_reg(u64& a, u64& b, bool up) {
    u64 mn = (a < b) ? a : b;
    u64 mx = (a < b) ? b : a;
    a = up ? mx : mn;
    b = up ? mn : mx;
}

__global__ __launch_bounds__(512, 1) void nms_fused(const float* __restrict__ conf,
                                                    const uint32_t* __restrict__ adj,
                                                    float* __restrict__ out) {
    __shared__ uint32_t buf[2][256][64];   // 128 KB; aliased as u64 keys[] in phase A
    __shared__ uint32_t ordL[NN];          // 8 KB: idx | (nonzero<<16)
    __shared__ uint32_t Ml[NN];            // 8 KB: pre-masked M'
    __shared__ uint32_t Sarr[WORDS];
    u64* keys = (u64*)&buf[0][0][0];       // KPAD(2047)=2174 -> 17.4 KB, fits

    const int bc = blockIdx.x;
    const int b  = bc >> 5;
    const int t  = threadIdx.x, wid = t >> 6, lane = t & 63;
    const float* cf = conf + (size_t)bc * NN;
    const uint32_t* ab = adj + (size_t)b * NN * WORDS;
    float* op = out + (size_t)bc * NN;

    // ---- Phase A: sort ----
    {
        const int g = 4 * t;
        float4 v = ((const float4*)cf)[t];
        float f0 = (v.x > PRE_THR) ? v.x : 0.0f;
        float f1 = (v.y > PRE_THR) ? v.y : 0.0f;
        float f2 = (v.z > PRE_THR) ? v.z : 0.0f;
        float f3 = (v.w > PRE_THR) ? v.w : 0.0f;
        u64 a0 = ((u64)__float_as_uint(f0) << 32) | (uint32_t)(NN - 1 - (g + 0));
        u64 a1 = ((u64)__float_as_uint(f1) << 32) | (uint32_t)(NN - 1 - (g + 1));
        u64 a2 = ((u64)__float_as_uint(f2) << 32) | (uint32_t)(NN - 1 - (g + 2));
        u64 a3 = ((u64)__float_as_uint(f3) << 32) | (uint32_t)(NN - 1 - (g + 3));
        ce_reg(a0, a1, true);
        ce_reg(a2, a3, false);
        bool up4 = ((g & 4) == 0);
        ce_reg(a0, a2, up4); ce_reg(a1, a3, up4);
        ce_reg(a0, a1, up4); ce_reg(a2, a3, up4);
        keys[KPAD(g + 0)] = a0; keys[KPAD(g + 1)] = a1;
        keys[KPAD(g + 2)] = a2; keys[KPAD(g + 3)] = a3;
    }
    __syncthreads();

    for (unsigned k = 8; k <= NN; k <<= 1) {
        unsigned j = k >> 1;
        while (j >= 2) {
            const unsigned h = j >> 1;
            {
                unsigned g  = (((unsigned)t & ~(h - 1)) << 2) | ((unsigned)t & (h - 1));
                bool up = ((g & k) == 0);
                u64 e0 = keys[KPAD(g)];
                u64 e1 = keys[KPAD(g + h)];
                u64 e2 = keys[KPAD(g + j)];
                u64 e3 = keys[KPAD(g + j + h)];
                ce_reg(e0, e2, up); ce_reg(e1, e3, up);
                ce_reg(e0, e1, up); ce_reg(e2, e3, up);
                keys[KPAD(g)]         = e0;
                keys[KPAD(g + h)]     = e1;
                keys[KPAD(g + j)]     = e2;
                keys[KPAD(g + j + h)] = e3;
            }
            __syncthreads();
            j >>= 2;
        }
        if (j == 1) {   // lone final stage: 1024 CEs, 2 per thread
#pragma unroll
            for (int it = 0; it < 2; ++it) {
                unsigned i = ((unsigned)t + it * 512u) << 1;
                bool up = ((i & k) == 0);
                u64 a = keys[KPAD(i)], d = keys[KPAD(i + 1)];
                ce_reg(a, d, up);
                keys[KPAD(i)] = a; keys[KPAD(i + 1)] = d;
            }
            __syncthreads();
        }
    }

    for (int r = t; r < NN; r += 512) {
        u64 kk = keys[KPAD(r)];
        uint32_t idx = (uint32_t)(NN - 1) - (uint32_t)(kk & 0xffffffffu);
        uint32_t nz  = ((uint32_t)(kk >> 32) != 0u) ? 0x10000u : 0u;
        ordL[r] = idx | nz;
    }
    __syncthreads();   // keys dead from here; buf reusable

    // ---- Phase B: extract (8 waves x 8 rank-blocks) ----
    {
        const int e = lane & 31, h = lane >> 5;
        for (int blk = wid * 8; blk < wid * 8 + 8; ++blk) {
            uint32_t ue = ordL[blk * 32 + e];
            int widx = (int)((ue & 0xffffu) >> 5);
            int bpos = (int)(ue & 31u);
            uint32_t wb[16];
#pragma unroll
            for (int k = 0; k < 16; ++k) {
                uint32_t ud = ordL[blk * 32 + k * 2 + h] & 0xffffu;
                wb[k] = ab[(size_t)ud * WORDS + widx];
            }
            uint32_t vM = 0;
#pragma unroll
            for (int k = 0; k < 16; ++k) {
                unsigned long long bal = __ballot(((wb[k] >> bpos) & 1u) != 0u);
                vM = (lane == 2 * k    ) ? (uint32_t)bal         : vM;
                vM = (lane == 2 * k + 1) ? (uint32_t)(bal >> 32) : vM;
            }
            if (lane < 32)
                Ml[blk * 32 + lane] = vM & (0xFFFFFFFEu << lane);
        }
    }
    __syncthreads();

    // ---- Phase C: producer/consumer scan ----
    // Fill chunk 0 (all 8 waves).
    for (int r = wid; r < 256; r += 8) {
        uint32_t ud = ordL[r] & 0xffffu;
        buf[0][r][lane] = ab[(size_t)ud * WORDS + lane];
    }
    __syncthreads();

    uint32_t S = 0;
    for (int c = 0; c < 8; ++c) {
        const int cb = c & 1, nb = cb ^ 1;
        if (wid != 0) {
            if (c < 7) {   // producers: stream chunk c+1 (7 waves)
                const int base = (c + 1) * 256;
                for (int r = wid - 1; r < 256; r += 7) {
                    uint32_t ud = ordL[base + r] & 0xffffu;
                    buf[nb][r][lane] = ab[(size_t)ud * WORDS + lane];
                }
            }
        } else {           // consumer: serial resolve of chunk c's 8 blocks
            for (int k = 0; k < 8; ++k) {
                const int blk = c * 8 + k;
                uint32_t u = ordL[blk * 32 + (lane & 31)];
                uint32_t m = Ml[blk * 32 + (lane & 31)];
                int wq = (int)(((u & 0xffffu) >> 5) << 2);
                int pm = __builtin_amdgcn_ds_bpermute(wq, (int)S);
                uint32_t rw[32];
#pragma unroll
                for (int d = 0; d < 32; ++d)
                    rw[d] = buf[cb][k * 32 + d][lane];
                bool a0 = (((u >> 16) & 1u) != 0u) && (((pm >> (u & 31u)) & 1) == 0);
                uint32_t alive = (uint32_t)__ballot((int)a0);
                if (alive) {
#pragma unroll
                    for (int d = 0; d < 32; ++d) {
                        uint32_t mk = (uint32_t)__builtin_amdgcn_readlane((int)m, d);
                        alive = (alive & (1u << d)) ? (alive & ~mk) : alive;
                    }
                    uint32_t acc = 0;
#pragma unroll
                    for (int d = 0; d < 32; ++d)
                        acc |= (alive & (1u << d)) ? rw[d] : 0u;
                    S |= acc;
                }
            }
        }
        __syncthreads();
    }
    if (wid == 0) Sarr[lane] = S;
    __syncthreads();

    // ---- Phase D: output (one float4 per thread) ----
    {
        int i4 = t * 4;
        float4 v = ((const float4*)cf)[t];
        uint32_t sw = Sarr[i4 >> 5];
        float4 o;
        o.x = (v.x > PRE_THR && !((sw >> ((i4 + 0) & 31)) & 1u)) ? v.x : 0.0f;
        o.y = (v.y > PRE_THR && !((sw >> ((i4 + 1) & 31)) & 1u)) ? v.y : 0.0f;
        o.z = (v.z > PRE_THR && !((sw >> ((i4 + 2) & 31)) & 1u)) ? v.z : 0.0f;
        o.w = (v.w > PRE_THR && !((sw >> ((i4 + 3) & 31)) & 1u)) ? v.w : 0.0f;
        ((float4*)op)[t] = o;
    }
}

extern "C" void kernel_launch(void* const* d_in, const int* in_sizes, int n_in,
                              void* d_out, int out_size, void* d_ws, size_t ws_size,
                              hipStream_t stream) {
    const float* bbs  = (const float*)d_in[0];   // [8,2048,4]
    const float* conf = (const float*)d_in[1];   // [8,32,2048]
    float* out = (float*)d_out;                  // [8,32,2048]

    const size_t adjB = (size_t)BB * NN * WORDS * sizeof(uint32_t);   // 4 MB
    uint32_t* adj = (uint32_t*)d_ws;
    if (ws_size < adjB) return;

    adj_kernel<<<dim3(NN / 16, BB), 256, 0, stream>>>(bbs, adj);
    nms_fused <<<BB * CC, 512, 0, stream>>>(conf, adj, out);
}